// Round 1
// baseline (654.646 us; speedup 1.0000x reference)
//
#include <hip/hip_runtime.h>

// Segment-sum: out[src[e], f] += edge_w[e, f]
// E = 1.6M edges, F = 32 features, N = 50000 nodes.
// Layout: edge = (2, E) int32 row-major -> src = edge[0..E), dst = edge[E..2E).
// edge_w = (E, 32) float32 row-major. out = (N, 32) float32.

constexpr int F = 32;

__global__ void __launch_bounds__(256) segsum_atomic(
    const int* __restrict__ src,
    const float* __restrict__ w,
    float* __restrict__ out,
    int E) {
    // 8 threads per edge, each handles a float4 (4 features).
    int idx = blockIdx.x * blockDim.x + threadIdx.x;
    int total = E * 8;
    if (idx >= total) return;
    int e = idx >> 3;
    int q = idx & 7;
    int s = src[e];
    const float4 v = *reinterpret_cast<const float4*>(w + (size_t)e * F + q * 4);
    float* o = out + (size_t)s * F + q * 4;
    // unsafeAtomicAdd -> global_atomic_add_f32 (no CAS loop).
    unsafeAtomicAdd(o + 0, v.x);
    unsafeAtomicAdd(o + 1, v.y);
    unsafeAtomicAdd(o + 2, v.z);
    unsafeAtomicAdd(o + 3, v.w);
}

extern "C" void kernel_launch(void* const* d_in, const int* in_sizes, int n_in,
                              void* d_out, int out_size, void* d_ws, size_t ws_size,
                              hipStream_t stream) {
    const int* edge = (const int*)d_in[0];       // (2, E) int32
    const float* edge_w = (const float*)d_in[1]; // (E, 32) float32
    const int E = in_sizes[0] / 2;
    const int* src = edge;                       // row 0 of edge

    float* out = (float*)d_out;                  // (N, 32) float32

    // Harness poisons d_out once and never re-zeros between timed replays;
    // atomics accumulate, so zero every call.
    hipMemsetAsync(out, 0, (size_t)out_size * sizeof(float), stream);

    int total = E * 8;
    int block = 256;
    int grid = (total + block - 1) / block;
    segsum_atomic<<<grid, block, 0, stream>>>(src, edge_w, out, E);
}

// Round 2
// 266.624 us; speedup vs baseline: 2.4553x; 2.4553x over previous
//
#include <hip/hip_runtime.h>

// Segment-sum via counting sort: out[s, f] = sum over edges e with src[e]==s of w[e, f].
// E = 1.6M edges, F = 32 features (128 B/row), N = 50000 nodes.
// edge = (2, E) int32; src = edge[0..E). edge_w = (E, 32) f32. out = (N, 32) f32.

constexpr int F = 32;
constexpr int SCAN_CHUNK = 256;

// ---- Phase 1: histogram of src ----
__global__ void __launch_bounds__(256) hist_kernel(
    const int* __restrict__ src, int* __restrict__ counts, int E) {
    int stride = gridDim.x * blockDim.x;
    for (int i = blockIdx.x * blockDim.x + threadIdx.x; i < E; i += stride)
        atomicAdd(&counts[src[i]], 1);
}

// ---- Phase 2a: per-chunk exclusive scan; emit chunk totals ----
__global__ void __launch_bounds__(SCAN_CHUNK) scan_blocks(
    const int* __restrict__ counts, int* __restrict__ offsets,
    int* __restrict__ blockSum, int N) {
    __shared__ int s[SCAN_CHUNK];
    int t = threadIdx.x;
    int i = blockIdx.x * SCAN_CHUNK + t;
    int v = (i < N) ? counts[i] : 0;
    s[t] = v;
    __syncthreads();
    for (int off = 1; off < SCAN_CHUNK; off <<= 1) {
        int add = (t >= off) ? s[t - off] : 0;
        __syncthreads();
        s[t] += add;
        __syncthreads();
    }
    if (i < N) offsets[i] = s[t] - v;  // exclusive
    if (t == 0) blockSum[blockIdx.x] = s[SCAN_CHUNK - 1];
}

// ---- Phase 2b: serial scan of chunk totals (<=256 of them) ----
__global__ void scan_root(const int* __restrict__ blockSum,
                          int* __restrict__ blockBase,
                          int* __restrict__ offsets, int NB, int N) {
    if (threadIdx.x == 0 && blockIdx.x == 0) {
        int run = 0;
        for (int b = 0; b < NB; ++b) { blockBase[b] = run; run += blockSum[b]; }
        offsets[N] = run;  // == E
    }
}

// ---- Phase 2c: add chunk bases; init cursors ----
__global__ void __launch_bounds__(SCAN_CHUNK) scan_apply(
    int* __restrict__ offsets, int* __restrict__ cursor,
    const int* __restrict__ blockBase, int N) {
    int i = blockIdx.x * SCAN_CHUNK + threadIdx.x;
    if (i < N) {
        int o = offsets[i] + blockBase[blockIdx.x];
        offsets[i] = o;
        cursor[i] = o;
    }
}

// ---- Phase 3: scatter edge indices into segment order ----
__global__ void __launch_bounds__(256) scatter_kernel(
    const int* __restrict__ src, int* __restrict__ cursor,
    int* __restrict__ sortedEdge, int E) {
    int stride = gridDim.x * blockDim.x;
    for (int i = blockIdx.x * blockDim.x + threadIdx.x; i < E; i += stride) {
        int s = src[i];
        int pos = atomicAdd(&cursor[s], 1);
        sortedEdge[pos] = i;
    }
}

// ---- Phase 4: per-node segmented sum; one wave per node ----
// 4 edges in flight: 16 lanes x float2 cover one 128 B edge row.
__global__ void __launch_bounds__(256) gather_kernel(
    const int* __restrict__ sortedEdge, const int* __restrict__ offsets,
    const float* __restrict__ w, float* __restrict__ out, int N) {
    int node = blockIdx.x * 4 + (threadIdx.x >> 6);
    if (node >= N) return;
    int lane = threadIdx.x & 63;
    int g = lane >> 4;    // edge slot 0..3
    int t = lane & 15;    // float2 slot within row
    int beg = offsets[node];
    int end = offsets[node + 1];
    float ax = 0.f, ay = 0.f;
    for (int i = beg + g; i < end; i += 4) {
        int e = sortedEdge[i];
        const float2 v = *reinterpret_cast<const float2*>(w + (size_t)e * F + t * 2);
        ax += v.x; ay += v.y;
    }
    // reduce the 4 edge slots (all share the same t)
    ax += __shfl_down(ax, 32); ay += __shfl_down(ay, 32);
    ax += __shfl_down(ax, 16); ay += __shfl_down(ay, 16);
    if (lane < 16) {
        float2 r; r.x = ax; r.y = ay;
        *reinterpret_cast<float2*>(out + (size_t)node * F + t * 2) = r;
    }
}

extern "C" void kernel_launch(void* const* d_in, const int* in_sizes, int n_in,
                              void* d_out, int out_size, void* d_ws, size_t ws_size,
                              hipStream_t stream) {
    const int* edge = (const int*)d_in[0];        // (2, E) int32
    const float* edge_w = (const float*)d_in[1];  // (E, 32) f32
    const int E = in_sizes[0] / 2;
    const int* src = edge;                        // row 0
    float* out = (float*)d_out;
    const int N = out_size / F;                   // 50000

    const int NB = (N + SCAN_CHUNK - 1) / SCAN_CHUNK;  // 196

    // workspace layout (ints)
    int* ws = (int*)d_ws;
    int* counts     = ws;               // N
    int* offsets    = counts + N;       // N+1
    int* cursor     = offsets + N + 1;  // N
    int* blockSum   = cursor + N;       // NB
    int* blockBase  = blockSum + NB;    // NB
    int* sortedEdge = blockBase + NB;   // E

    hipMemsetAsync(counts, 0, (size_t)N * sizeof(int), stream);

    hist_kernel<<<2048, 256, 0, stream>>>(src, counts, E);
    scan_blocks<<<NB, SCAN_CHUNK, 0, stream>>>(counts, offsets, blockSum, N);
    scan_root<<<1, 64, 0, stream>>>(blockSum, blockBase, offsets, NB, N);
    scan_apply<<<NB, SCAN_CHUNK, 0, stream>>>(offsets, cursor, blockBase, N);
    scatter_kernel<<<2048, 256, 0, stream>>>(src, cursor, sortedEdge, E);
    gather_kernel<<<(N + 3) / 4, 256, 0, stream>>>(sortedEdge, offsets, edge_w, out, N);
}